// Round 3
// baseline (32060.757 us; speedup 1.0000x reference)
//
#include <hip/hip_runtime.h>
#include <hip/hip_cooperative_groups.h>
#include <math.h>

namespace cgx = cooperative_groups;

typedef __attribute__((ext_vector_type(8))) _Float16 half8;
typedef __attribute__((ext_vector_type(4))) _Float16 half4;
typedef __attribute__((ext_vector_type(4))) float    f32x4;

#define NSTEP 256
#define NB    1024
#define HID   256
#define BH    262144
#define INV2K 4.8828125e-4f   // 1/2048

__device__ __forceinline__ float sigf(float x){ return 1.f/(1.f+expf(-x)); }
__device__ __forceinline__ void splitf(float v, _Float16& h, _Float16& l){
    h = (_Float16)v; l = (_Float16)((v - (float)h)*2048.f);
}

// ---------------------------------------------------------------------------
// Weight pre-split (transpose + fp16 hi/lo): out[n][k] from up to 3 stacked
// sources (row-major [k][ldn]), k-boundaries kb1/kb2.
// ---------------------------------------------------------------------------
__global__ __launch_bounds__(256)
void wsplit_k(const float* __restrict__ s0, const float* __restrict__ s1,
              const float* __restrict__ s2, int K, int N, int ldn,
              int kb1, int kb2, _Float16* __restrict__ oh, _Float16* __restrict__ ol)
{
    int idx = blockIdx.x*256 + threadIdx.x;
    if (idx >= N*K) return;
    int n = idx / K, k = idx - n*K;
    const float* s = (k < kb1) ? &s0[(size_t)k*ldn]
                   : (k < kb2) ? &s1[(size_t)(k-kb1)*ldn]
                               : &s2[(size_t)(k-kb2)*ldn];
    float v = s[n];
    _Float16 h, l; splitf(v, h, l);
    oh[idx] = h; ol[idx] = l;
}

// z-column (col 1024) of cell1 weights -> contiguous fp32 [768]
__global__ void wz_k(const float* __restrict__ W01, const float* __restrict__ U21,
                     const float* __restrict__ U11, float* __restrict__ wz)
{
    int k = blockIdx.x*256 + threadIdx.x;
    if (k >= 768) return;
    wz[k] = (k < 256) ? W01[(size_t)k*1025 + 1024]
          : (k < 512) ? U21[(size_t)(k-256)*1025 + 1024]
                      : U11[(size_t)(k-512)*1025 + 1024];
}

__global__ __launch_bounds__(256)
void init_k(_Float16* h1h, _Float16* h1l, _Float16* h2h, _Float16* h2l, float* z1)
{
    int i = blockIdx.x*256 + threadIdx.x;
    if (i < BH) {
        h1h[i]=(_Float16)0.f; h1l[i]=(_Float16)0.f;
        h2h[i]=(_Float16)0.f; h2l[i]=(_Float16)0.f;
    }
    if (i < NB) z1[i] = 1.f;
}

// ---------------------------------------------------------------------------
// LDS-free split-fp16 MFMA GEMM for encoder/head. C = act(A[Mx256] @ W + b).
// Block 512 thr / 8 waves; tile 64 rows x 64 cols; wave: rows (w&1)*32,
// cols (w>>1)*16. AIN 0: A fp32; 1: A split hi/lo. AOUT 0: relu+split; 1: tanh f32.
// ---------------------------------------------------------------------------
template<int AIN, int AOUT, int NC>
__global__ __launch_bounds__(512)
void enc_k(const float* __restrict__ Af, const _Float16* __restrict__ Ah,
           const _Float16* __restrict__ Al,
           const _Float16* __restrict__ Bh, const _Float16* __restrict__ Bl,
           const float* __restrict__ bias,
           _Float16* __restrict__ Oh, _Float16* __restrict__ Ol,
           float* __restrict__ Of)
{
    const int tid = threadIdx.x, wid = tid>>6, lane = tid&63;
    const int rh = wid&1, cq = wid>>1;
    const int lr = lane&15, kq = (lane>>4)<<3;
    const size_t r0 = (size_t)blockIdx.x*64;
    const int col = blockIdx.y*64 + cq*16 + lr;

    f32x4 am[2] = {}, ax[2] = {};
    size_t aoff[2];
    aoff[0] = (r0 + rh*32 + lr)*256 + kq;
    aoff[1] = aoff[0] + 16*256;
    const size_t boff = (size_t)col*256 + kq;

#pragma unroll
    for (int kb = 0; kb < 8; ++kb) {
        int k = kb*32;
        half8 bh8 = *(const half8*)(Bh + boff + k);
        half8 bl8 = *(const half8*)(Bl + boff + k);
#pragma unroll
        for (int rf = 0; rf < 2; ++rf) {
            half8 ah8, al8;
            if (AIN == 0) {
                float4 a0 = *(const float4*)(Af + aoff[rf] + k);
                float4 a1 = *(const float4*)(Af + aoff[rf] + k + 4);
                float av[8] = {a0.x,a0.y,a0.z,a0.w,a1.x,a1.y,a1.z,a1.w};
#pragma unroll
                for (int i=0;i<8;++i){ _Float16 h,l; splitf(av[i],h,l); ah8[i]=h; al8[i]=l; }
            } else {
                ah8 = *(const half8*)(Ah + aoff[rf] + k);
                al8 = *(const half8*)(Al + aoff[rf] + k);
            }
            am[rf] = __builtin_amdgcn_mfma_f32_16x16x32_f16(ah8, bh8, am[rf],0,0,0);
            ax[rf] = __builtin_amdgcn_mfma_f32_16x16x32_f16(ah8, bl8, ax[rf],0,0,0);
            ax[rf] = __builtin_amdgcn_mfma_f32_16x16x32_f16(al8, bh8, ax[rf],0,0,0);
        }
    }
    float bv = bias[col];
#pragma unroll
    for (int rf=0; rf<2; ++rf)
#pragma unroll
        for (int q=0;q<4;++q) {
            size_t row = r0 + rh*32 + rf*16 + ((lane>>4)<<2) + q;
            float v = am[rf][q] + ax[rf][q]*INV2K + bv;
            if (AOUT == 0) {
                v = fmaxf(v, 0.f);
                _Float16 h,l; splitf(v,h,l);
                Oh[row*NC + col] = h; Ol[row*NC + col] = l;
            } else {
                Of[row*NC + col] = tanhf(v);
            }
        }
}

// ---------------------------------------------------------------------------
// Persistent cooperative recurrence kernel. 256 blocks x 512 thr (8 waves).
// Block (bp,cg): rows bp*64..+64, j-cols cg*16..+16 (x4 gates). Wave w:
// gate w>>1, row-half w&1. c1/c2 in registers; h states split fp16 ping-pong.
// cell2 W slice resident in LDS (XOR-swizzled); cell1 W streamed from L2.
// ---------------------------------------------------------------------------
struct SeqArgs {
    const _Float16 *XeH, *XeL;
    _Float16 *EmH, *EmL;
    const _Float16 *W1h, *W1l, *W2h, *W2l;
    const float *b1, *b2, *wz, *noise1;
    _Float16 *h1h[2], *h1l[2], *h2h[2], *h2l[2];
    float *zb[2];
};

#define SEQ_SMEM (131072 + 16384)

__global__ __launch_bounds__(512, 1)
void hm_seq_k(SeqArgs a)
{
    extern __shared__ __align__(16) char smem[];
    float* ex = (float*)(smem + 131072);      // [4][64][16] f32 gate exchange

    cgx::grid_group grid = cgx::this_grid();

    const int tid  = threadIdx.x, wid = tid>>6, lane = tid&63;
    const int bid  = blockIdx.x;
    const int cgp  = ((bid & 7) << 1) | ((bid >> 3) & 1);   // col-group 0..15 (XCD-local)
    const int bp   = bid >> 4;                              // row-panel 0..15
    const int g    = wid >> 1, rh = wid & 1;
    const int lr   = lane & 15, kq = (lane>>4) << 3;
    const int R    = bp*64 + rh*32;

    // ---- one-time: cell2 W slice -> LDS (XOR-swizzled, 64 cols x 512 k, hi/lo)
    {
        int c = tid >> 3, sub = tid & 7;
        int gcol = (c>>4)*256 + cgp*16 + (c&15);
#pragma unroll
        for (int i = 0; i < 8; ++i) {
            int k = sub*64 + i*8;
            half8 hv = *(const half8*)(a.W2h + (size_t)gcol*512 + k);
            half8 lv = *(const half8*)(a.W2l + (size_t)gcol*512 + k);
            int byt = ((c*512 + k)*2) ^ ((c&7)<<4);
            *(half8*)(smem + byt) = hv;
            *(half8*)(smem + 65536 + byt) = lv;
        }
    }
    __syncthreads();

    float c1r[2] = {0.f, 0.f}, c2r[2] = {0.f, 0.f};

    const int cwg = g*256 + cgp*16 + lr;          // fs/W column for this lane
    const _Float16* B1h = a.W1h + (size_t)cwg*768 + kq;
    const _Float16* B1l = a.W1l + (size_t)cwg*768 + kq;
    const int c2c = g*16 + lr;                    // LDS col index for cell2 B
    const float bv1 = a.b1[cwg];
    const float bv2 = a.b2[cwg];

    size_t aoff[2];
    aoff[0] = (size_t)(R + lr)*HID + kq;
    aoff[1] = aoff[0] + 16*HID;
    const int rowA[2] = { R + lr, R + 16 + lr };

    for (int t = 0; t < NSTEP; ++t) {
        const int cur = t & 1, nxt = cur ^ 1;
        const _Float16 *h1hc = a.h1h[cur], *h1lc = a.h1l[cur];
        const _Float16 *h2hc = a.h2h[cur], *h2lc = a.h2l[cur];
        const float* zc = a.zb[cur];
        float*       zn = a.zb[nxt];
        const _Float16* xeh = a.XeH + (size_t)t*BH;
        const _Float16* xel = a.XeL + (size_t)t*BH;

        // ================= phase 1: cell1 fs1 = [h1 | z*h2 | xe] @ W1 =======
        f32x4 am[2] = {}, ax[2] = {};
        const bool zs[2] = { zc[rowA[0]] != 0.f, zc[rowA[1]] != 0.f };

#pragma unroll
        for (int kb = 0; kb < 8; ++kb) {          // region h1: k 0..255
            int k = kb*32;
            half8 bh8 = *(const half8*)(B1h + k);
            half8 bl8 = *(const half8*)(B1l + k);
#pragma unroll
            for (int rf = 0; rf < 2; ++rf) {
                half8 ah8 = *(const half8*)(h1hc + aoff[rf] + k);
                half8 al8 = *(const half8*)(h1lc + aoff[rf] + k);
                am[rf] = __builtin_amdgcn_mfma_f32_16x16x32_f16(ah8, bh8, am[rf],0,0,0);
                ax[rf] = __builtin_amdgcn_mfma_f32_16x16x32_f16(ah8, bl8, ax[rf],0,0,0);
                ax[rf] = __builtin_amdgcn_mfma_f32_16x16x32_f16(al8, bh8, ax[rf],0,0,0);
            }
        }
#pragma unroll
        for (int kb = 0; kb < 8; ++kb) {          // region z*h2: k 256..511
            int k = kb*32;
            half8 bh8 = *(const half8*)(B1h + 256 + k);
            half8 bl8 = *(const half8*)(B1l + 256 + k);
#pragma unroll
            for (int rf = 0; rf < 2; ++rf) {
                half8 ah8 = *(const half8*)(h2hc + aoff[rf] + k);
                half8 al8 = *(const half8*)(h2lc + aoff[rf] + k);
                if (!zs[rf]) { ah8 = half8{}; al8 = half8{}; }
                am[rf] = __builtin_amdgcn_mfma_f32_16x16x32_f16(ah8, bh8, am[rf],0,0,0);
                ax[rf] = __builtin_amdgcn_mfma_f32_16x16x32_f16(ah8, bl8, ax[rf],0,0,0);
                ax[rf] = __builtin_amdgcn_mfma_f32_16x16x32_f16(al8, bh8, ax[rf],0,0,0);
            }
        }
#pragma unroll
        for (int kb = 0; kb < 8; ++kb) {          // region xe: k 512..767
            int k = kb*32;
            half8 bh8 = *(const half8*)(B1h + 512 + k);
            half8 bl8 = *(const half8*)(B1l + 512 + k);
#pragma unroll
            for (int rf = 0; rf < 2; ++rf) {
                half8 ah8 = *(const half8*)(xeh + aoff[rf] + k);
                half8 al8 = *(const half8*)(xel + aoff[rf] + k);
                am[rf] = __builtin_amdgcn_mfma_f32_16x16x32_f16(ah8, bh8, am[rf],0,0,0);
                ax[rf] = __builtin_amdgcn_mfma_f32_16x16x32_f16(ah8, bl8, ax[rf],0,0,0);
                ax[rf] = __builtin_amdgcn_mfma_f32_16x16x32_f16(al8, bh8, ax[rf],0,0,0);
            }
        }

        // epilogue 1: activate -> ex -> c1/h1 update
#pragma unroll
        for (int rf=0;rf<2;++rf)
#pragma unroll
            for (int q=0;q<4;++q) {
                float v = am[rf][q] + ax[rf][q]*INV2K + bv1;
                v = (g<3) ? sigf(v) : tanhf(v);
                int er = rh*32 + rf*16 + ((lane>>4)<<2) + q;
                ex[(g*64 + er)*16 + lr] = v;
            }
        __syncthreads();
#pragma unroll
        for (int is=0; is<2; ++is) {
            int s = tid + is*512;
            int row = s >> 4, cj = s & 15;
            float f  = ex[(0*64+row)*16+cj], i = ex[(1*64+row)*16+cj];
            float o  = ex[(2*64+row)*16+cj], gg = ex[(3*64+row)*16+cj];
            float cn = f*c1r[is] + i*gg;
            float hn = o*tanhf(cn);
            c1r[is] = cn;
            size_t ga = (size_t)(bp*64+row)*HID + cgp*16 + cj;
            _Float16 hh, hl; splitf(hn, hh, hl);
            a.h1h[nxt][ga] = hh; a.h1l[nxt][ga] = hl;
        }

        // z-column (exact fp32) by cg==0 blocks
        if (cgp == 0) {
            int row = tid >> 3, sub = tid & 7;
            int grow = bp*64 + row;
            float zcv = zc[grow];
            float acc = 0.f;
            size_t rb = (size_t)grow * HID;
#pragma unroll
            for (int i = 0; i < 24; ++i) {
                int k = sub*4 + i*32;
                const _Float16 *ph, *pl; float sc = 1.f;
                if (k < 256)      { ph = h1hc + rb + k;       pl = h1lc + rb + k; }
                else if (k < 512) { ph = h2hc + rb + (k-256); pl = h2lc + rb + (k-256); sc = zcv; }
                else              { ph = xeh  + rb + (k-512); pl = xel  + rb + (k-512); }
                half4 hv = *(const half4*)ph;
                half4 lv = *(const half4*)pl;
#pragma unroll
                for (int j=0;j<4;++j)
                    acc = fmaf(((float)hv[j] + (float)lv[j]*INV2K)*sc, a.wz[k+j], acc);
            }
            acc += __shfl_xor(acc, 1);
            acc += __shfl_xor(acc, 2);
            acc += __shfl_xor(acc, 4);
            if (sub == 0) {
                float fsz = acc + a.b1[1024];
                float zh = fminf(fmaxf((0.1f*fsz + 1.f)*0.5f, 0.05f), 0.95f);
                zn[grow] = (a.noise1[(size_t)t*NB + grow] < zh) ? 1.f : 0.f;
            }
        }
        grid.sync();

        // ================= phase 2: cell2 fs2 = [h2 | z1n*h1n] @ W2 =========
        const _Float16 *h1hn = a.h1h[nxt], *h1ln = a.h1l[nxt];
        f32x4 bm[2] = {}, bx[2] = {};
        const bool zs2[2] = { zn[rowA[0]] != 0.f, zn[rowA[1]] != 0.f };

#pragma unroll
        for (int kb = 0; kb < 8; ++kb) {          // region h2: k 0..255
            int k = kb*32;
            int byt = ((c2c*512 + kq + k)*2) ^ ((c2c&7)<<4);
            half8 bh8 = *(const half8*)(smem + byt);
            half8 bl8 = *(const half8*)(smem + 65536 + byt);
#pragma unroll
            for (int rf = 0; rf < 2; ++rf) {
                half8 ah8 = *(const half8*)(h2hc + aoff[rf] + k);
                half8 al8 = *(const half8*)(h2lc + aoff[rf] + k);
                bm[rf] = __builtin_amdgcn_mfma_f32_16x16x32_f16(ah8, bh8, bm[rf],0,0,0);
                bx[rf] = __builtin_amdgcn_mfma_f32_16x16x32_f16(ah8, bl8, bx[rf],0,0,0);
                bx[rf] = __builtin_amdgcn_mfma_f32_16x16x32_f16(al8, bh8, bx[rf],0,0,0);
            }
        }
#pragma unroll
        for (int kb = 0; kb < 8; ++kb) {          // region z1n*h1n: k 256..511
            int k = kb*32;
            int byt = ((c2c*512 + kq + 256 + k)*2) ^ ((c2c&7)<<4);
            half8 bh8 = *(const half8*)(smem + byt);
            half8 bl8 = *(const half8*)(smem + 65536 + byt);
#pragma unroll
            for (int rf = 0; rf < 2; ++rf) {
                half8 ah8 = *(const half8*)(h1hn + aoff[rf] + k);
                half8 al8 = *(const half8*)(h1ln + aoff[rf] + k);
                if (!zs2[rf]) { ah8 = half8{}; al8 = half8{}; }
                bm[rf] = __builtin_amdgcn_mfma_f32_16x16x32_f16(ah8, bh8, bm[rf],0,0,0);
                bx[rf] = __builtin_amdgcn_mfma_f32_16x16x32_f16(ah8, bl8, bx[rf],0,0,0);
                bx[rf] = __builtin_amdgcn_mfma_f32_16x16x32_f16(al8, bh8, bx[rf],0,0,0);
            }
        }

        // epilogue 2
#pragma unroll
        for (int rf=0;rf<2;++rf)
#pragma unroll
            for (int q=0;q<4;++q) {
                float v = bm[rf][q] + bx[rf][q]*INV2K + bv2;
                v = (g<3) ? sigf(v) : tanhf(v);
                int er = rh*32 + rf*16 + ((lane>>4)<<2) + q;
                ex[(g*64 + er)*16 + lr] = v;
            }
        __syncthreads();
#pragma unroll
        for (int is=0; is<2; ++is) {
            int s = tid + is*512;
            int row = s >> 4, cj = s & 15;
            float f  = ex[(0*64+row)*16+cj], i = ex[(1*64+row)*16+cj];
            float o  = ex[(2*64+row)*16+cj], gg = ex[(3*64+row)*16+cj];
            bool  zv = zn[bp*64+row] != 0.f;
            float cn = zv ? (f*c2r[is] + i*gg) : c2r[is];
            float hn = o*tanhf(cn);
            c2r[is] = cn;
            size_t ga = (size_t)(bp*64+row)*HID + cgp*16 + cj;
            _Float16 hh, hl; splitf(hn, hh, hl);
            a.h2h[nxt][ga] = hh; a.h2l[nxt][ga] = hl;
            a.EmH[(size_t)t*BH + ga] = hh; a.EmL[(size_t)t*BH + ga] = hl;
        }
        grid.sync();
    }
}

// ---------------------------------------------------------------------------
extern "C" void kernel_launch(void* const* d_in, const int* in_sizes, int n_in,
                              void* d_out, int out_size, void* d_ws, size_t ws_size,
                              hipStream_t stream)
{
    const float* x     = (const float*)d_in[0];
    const float* n1    = (const float*)d_in[1];
    const float* We1   = (const float*)d_in[3];
    const float* be1   = (const float*)d_in[4];
    const float* We2   = (const float*)d_in[5];
    const float* be2   = (const float*)d_in[6];
    const float* U11_1 = (const float*)d_in[7];
    const float* U21_1 = (const float*)d_in[8];
    const float* W01_1 = (const float*)d_in[9];
    const float* b1    = (const float*)d_in[10];
    const float* U11_2 = (const float*)d_in[11];
    const float* W01_2 = (const float*)d_in[12];
    const float* b2    = (const float*)d_in[13];
    const float* Wh    = (const float*)d_in[14];
    const float* bh    = (const float*)d_in[15];
    const float* Wp    = (const float*)d_in[16];
    const float* bp_   = (const float*)d_in[17];
    float* out = (float*)d_out;

    char* p = (char*)d_ws;
    auto alloc = [&](size_t bytes){ char* q = p; p += (bytes + 255) & ~(size_t)255; return q; };
    _Float16* XeH  = (_Float16*)alloc((size_t)NSTEP*BH*2);
    _Float16* XeL  = (_Float16*)alloc((size_t)NSTEP*BH*2);
    _Float16* EmH  = (_Float16*)alloc((size_t)NSTEP*BH*2);   // xe1 temp, then emb
    _Float16* EmL  = (_Float16*)alloc((size_t)NSTEP*BH*2);
    _Float16* Wt1h = (_Float16*)alloc((size_t)1024*768*2);
    _Float16* Wt1l = (_Float16*)alloc((size_t)1024*768*2);
    _Float16* Wt2h = (_Float16*)alloc((size_t)1024*512*2);
    _Float16* Wt2l = (_Float16*)alloc((size_t)1024*512*2);
    _Float16* We1h = (_Float16*)alloc(256*256*2);
    _Float16* We1l = (_Float16*)alloc(256*256*2);
    _Float16* We2h = (_Float16*)alloc(256*256*2);
    _Float16* We2l = (_Float16*)alloc(256*256*2);
    _Float16* Whh  = (_Float16*)alloc(256*256*2);
    _Float16* Whl  = (_Float16*)alloc(256*256*2);
    _Float16* Wph  = (_Float16*)alloc(64*256*2);
    _Float16* Wpl  = (_Float16*)alloc(64*256*2);
    float*    wz1  = (float*)alloc(768*4);
    _Float16* hbuf = (_Float16*)alloc((size_t)8*BH*2);       // h1h0,h1l0..h2l1 via offsets
    float*    z0   = (float*)alloc(NB*4);
    float*    z1b  = (float*)alloc(NB*4);
    if (ws_size < (size_t)(p - (char*)d_ws)) return;

    SeqArgs sa;
    sa.XeH = XeH; sa.XeL = XeL; sa.EmH = EmH; sa.EmL = EmL;
    sa.W1h = Wt1h; sa.W1l = Wt1l; sa.W2h = Wt2h; sa.W2l = Wt2l;
    sa.b1 = b1; sa.b2 = b2; sa.wz = wz1; sa.noise1 = n1;
    sa.h1h[0] = hbuf + 0*(size_t)BH; sa.h1h[1] = hbuf + 1*(size_t)BH;
    sa.h1l[0] = hbuf + 2*(size_t)BH; sa.h1l[1] = hbuf + 3*(size_t)BH;
    sa.h2h[0] = hbuf + 4*(size_t)BH; sa.h2h[1] = hbuf + 5*(size_t)BH;
    sa.h2l[0] = hbuf + 6*(size_t)BH; sa.h2l[1] = hbuf + 7*(size_t)BH;
    sa.zb[0] = z0; sa.zb[1] = z1b;

    // ---- prep ----
    wsplit_k<<<dim3(3072), 256, 0, stream>>>(W01_1, U21_1, U11_1, 768, 1024, 1025, 256, 512, Wt1h, Wt1l);
    wsplit_k<<<dim3(2048), 256, 0, stream>>>(W01_2, U11_2, nullptr, 512, 1024, 1025, 256, 512, Wt2h, Wt2l);
    wsplit_k<<<dim3(256),  256, 0, stream>>>(We1, nullptr, nullptr, 256, 256, 256, 256, 256, We1h, We1l);
    wsplit_k<<<dim3(256),  256, 0, stream>>>(We2, nullptr, nullptr, 256, 256, 256, 256, 256, We2h, We2l);
    wsplit_k<<<dim3(256),  256, 0, stream>>>(Wh,  nullptr, nullptr, 256, 256, 256, 256, 256, Whh,  Whl);
    wsplit_k<<<dim3(64),   256, 0, stream>>>(Wp,  nullptr, nullptr, 256, 64, 64, 256, 256, Wph, Wpl);
    wz_k<<<dim3(3), 256, 0, stream>>>(W01_1, U21_1, U11_1, wz1);
    init_k<<<dim3(1024), 256, 0, stream>>>(sa.h1h[0], sa.h1l[0], sa.h2h[0], sa.h2l[0], z0);

    // ---- encoder: xe = relu(relu(x@We1+be1)@We2+be2), stored split ----
    enc_k<0,0,256><<<dim3(4096,4), 512, 0, stream>>>(x, nullptr, nullptr, We1h, We1l, be1, EmH, EmL, nullptr);
    enc_k<1,0,256><<<dim3(4096,4), 512, 0, stream>>>(nullptr, EmH, EmL, We2h, We2l, be2, XeH, XeL, nullptr);

    // ---- recurrence: one persistent cooperative kernel ----
    hipFuncSetAttribute((const void*)hm_seq_k, hipFuncAttributeMaxDynamicSharedMemorySize, SEQ_SMEM);
    void* kargs[] = { (void*)&sa };
    hipLaunchCooperativeKernel((const void*)hm_seq_k, dim3(256), dim3(512), kargs, SEQ_SMEM, stream);

    // ---- head: out = tanh(relu(emb@Wh+bh)@Wp+bp) ----
    enc_k<1,0,256><<<dim3(4096,4), 512, 0, stream>>>(nullptr, EmH, EmL, Whh, Whl, bh, XeH, XeL, nullptr);
    enc_k<1,1,64><<<dim3(4096,1), 512, 0, stream>>>(nullptr, XeH, XeL, Wph, Wpl, bp_, nullptr, nullptr, out);
}

// Round 4
// 9813.126 us; speedup vs baseline: 3.2671x; 3.2671x over previous
//
#include <hip/hip_runtime.h>
#include <math.h>

typedef __attribute__((ext_vector_type(8))) _Float16 half8;
typedef __attribute__((ext_vector_type(4))) _Float16 half4;
typedef __attribute__((ext_vector_type(4))) float    f32x4;

#define NSTEP 256
#define NB    1024
#define HID   256
#define BH    262144          // NB*HID
#define LK    40              // padded LDS row stride (f16 units)
#define INV2K 4.8828125e-4f   // 1/2048

__device__ __forceinline__ float sigf(float x){ return 1.f/(1.f+expf(-x)); }
__device__ __forceinline__ void splitf(float v, _Float16& h, _Float16& l){
    h = (_Float16)v; l = (_Float16)((v - (float)h)*2048.f);
}

// ---------------------------------------------------------------------------
// Weight pre-split (transpose + fp16 hi/lo): out[n][k] from up to 3 stacked
// sources (row-major [k][ldn]), k-boundaries kb1/kb2.
// ---------------------------------------------------------------------------
__global__ __launch_bounds__(256)
void wsplit_k(const float* __restrict__ s0, const float* __restrict__ s1,
              const float* __restrict__ s2, int K, int N, int ldn,
              int kb1, int kb2, _Float16* __restrict__ oh, _Float16* __restrict__ ol)
{
    int idx = blockIdx.x*256 + threadIdx.x;
    if (idx >= N*K) return;
    int n = idx / K, k = idx - n*K;
    const float* s = (k < kb1) ? &s0[(size_t)k*ldn]
                   : (k < kb2) ? &s1[(size_t)(k-kb1)*ldn]
                               : &s2[(size_t)(k-kb2)*ldn];
    float v = s[n];
    _Float16 h, l; splitf(v, h, l);
    oh[idx] = h; ol[idx] = l;
}

// z-column (col 1024) of cell1 weights -> contiguous fp32 [768]
__global__ void wz_k(const float* __restrict__ W01, const float* __restrict__ U21,
                     const float* __restrict__ U11, float* __restrict__ wz)
{
    int k = blockIdx.x*256 + threadIdx.x;
    if (k >= 768) return;
    wz[k] = (k < 256) ? W01[(size_t)k*1025 + 1024]
          : (k < 512) ? U21[(size_t)(k-256)*1025 + 1024]
                      : U11[(size_t)(k-512)*1025 + 1024];
}

__global__ __launch_bounds__(256)
void init_k(_Float16* h1h, _Float16* h1l, float* c1, float* c2, float* z1)
{
    int i = blockIdx.x*256 + threadIdx.x;
    if (i < BH) {
        h1h[i]=(_Float16)0.f; h1l[i]=(_Float16)0.f;
        c1[i]=0.f; c2[i]=0.f;
    }
    if (i < NB) z1[i] = 1.f;
}

__global__ __launch_bounds__(256)
void zslot_k(_Float16* sh, _Float16* sl)     // zero slot 0 (h2 init)
{
    int i = blockIdx.x*256 + threadIdx.x;    // BH/4 threads
    *(half4*)&sh[(size_t)i*4] = half4{};
    *(half4*)&sl[(size_t)i*4] = half4{};
}

// ---------------------------------------------------------------------------
// Fused HM-LSTM cell step. grid(16 jTiles, 16 rowTiles), 256 thr / 4 waves.
// Block: 64 rows x (4 gates x 16 j). Wave w: rows (w&1)*32, cols (w>>1)*32.
// K-loop: double-buffered LDS, register prefetch 1 tile ahead, 1 barrier/iter.
// CELL=1: A = [h1 | z*h2 | xe] K=768; outputs h1n(split), c1 in-place, z1n.
// CELL=2: A = [h2 | z1n*h1n]  K=512; outputs h2n->Em slot (split), c2 in-place.
// ---------------------------------------------------------------------------
template<int CELL>
__global__ __launch_bounds__(256)
void cell_k(const _Float16* __restrict__ A0h, const _Float16* __restrict__ A0l,
            const _Float16* __restrict__ A1h, const _Float16* __restrict__ A1l,
            const _Float16* __restrict__ A2h, const _Float16* __restrict__ A2l,
            const float* __restrict__ zrow,
            const _Float16* __restrict__ Wth, const _Float16* __restrict__ Wtl,
            const float* __restrict__ bias, const float* __restrict__ wz,
            const float* __restrict__ noise, float* __restrict__ cbuf,
            _Float16* __restrict__ Hh, _Float16* __restrict__ Hl,
            float* __restrict__ z_out)
{
    constexpr int K  = (CELL==1) ? 768 : 512;
    constexpr int NT = K/32;
    __shared__ __align__(16) char smem[40960];   // 2 bufs x (Ah,Al,Bh,Bl) 5120B each
    float* ex = (float*)smem;                    // epilogue overlay [4][64][16] f32

    const int tid  = threadIdx.x;
    const int bx   = blockIdx.x, by = blockIdx.y;
    const int R0   = by*64, j0 = bx*16;
    const int rh   = (tid>>6)&1, ch = tid>>7;
    const int lane = tid&63, lr = lane&15, kq = (lane>>4)<<3;
    const int arow = tid>>2, seg = tid&3;        // staging: 64 rows x 4 k-segs

    const size_t abase = (size_t)(R0+arow)*HID + seg*8;
    const bool   zv    = zrow[R0+arow] != 0.f;
    const int    wcol  = tid>>2;
    const int    gcol  = (wcol>>4)*256 + j0 + (wcol&15);
    const size_t wbase = (size_t)gcol*K + seg*8;

    f32x4 am[2][2], ax[2][2];
#pragma unroll
    for (int r=0;r<2;++r)
#pragma unroll
        for (int c=0;c<2;++c){ am[r][c]=(f32x4)0.f; ax[r][c]=(f32x4)0.f; }
    float zacc = 0.f;
    const bool do_z = (CELL==1) && (bx==0);

    half8 rah, ral, rwh, rwl;
    auto load_tile = [&](int k0, half8& ah, half8& al, half8& wh, half8& wl) {
        const _Float16 *ph, *pl; bool zs = false;
        if (CELL==1) {
            if (k0 < 256)      { ph = A0h + abase + k0;       pl = A0l + abase + k0; }
            else if (k0 < 512) { ph = A1h + abase + (k0-256); pl = A1l + abase + (k0-256); zs = true; }
            else               { ph = A2h + abase + (k0-512); pl = A2l + abase + (k0-512); }
        } else {
            if (k0 < 256)      { ph = A0h + abase + k0;       pl = A0l + abase + k0; }
            else               { ph = A1h + abase + (k0-256); pl = A1l + abase + (k0-256); zs = true; }
        }
        ah = *(const half8*)ph;
        al = *(const half8*)pl;
        if (zs && !zv) { ah = half8{}; al = half8{}; }
        wh = *(const half8*)(Wth + wbase + k0);
        wl = *(const half8*)(Wtl + wbase + k0);
    };
    auto store_tile = [&](int buf) {
        char* bs = smem + buf*20480;
        *(half8*)((_Float16*)(bs        ) + arow*LK + seg*8) = rah;
        *(half8*)((_Float16*)(bs +  5120) + arow*LK + seg*8) = ral;
        *(half8*)((_Float16*)(bs + 10240) + wcol*LK + seg*8) = rwh;
        *(half8*)((_Float16*)(bs + 15360) + wcol*LK + seg*8) = rwl;
    };

    load_tile(0, rah, ral, rwh, rwl);
    store_tile(0);

#pragma unroll 2
    for (int kb = 0; kb < NT; ++kb) {
        const int buf = kb & 1;
        half8 nah, nal, nwh, nwl;
        if (kb+1 < NT) load_tile((kb+1)*32, nah, nal, nwh, nwl);
        __syncthreads();
        const char* bs = smem + buf*20480;
        const _Float16* LAh = (const _Float16*)bs;
        const _Float16* LAl = (const _Float16*)(bs +  5120);
        const _Float16* LBh = (const _Float16*)(bs + 10240);
        const _Float16* LBl = (const _Float16*)(bs + 15360);
        half8 fah[2], fal[2], fbh[2], fbl[2];
#pragma unroll
        for (int rf=0;rf<2;++rf) {
            fah[rf] = *(const half8*)(LAh + (rh*32+rf*16+lr)*LK + kq);
            fal[rf] = *(const half8*)(LAl + (rh*32+rf*16+lr)*LK + kq);
        }
#pragma unroll
        for (int cf=0;cf<2;++cf) {
            fbh[cf] = *(const half8*)(LBh + (ch*32+cf*16+lr)*LK + kq);
            fbl[cf] = *(const half8*)(LBl + (ch*32+cf*16+lr)*LK + kq);
        }
#pragma unroll
        for (int cf=0;cf<2;++cf)
#pragma unroll
            for (int rf=0;rf<2;++rf) {
                am[rf][cf] = __builtin_amdgcn_mfma_f32_16x16x32_f16(fah[rf], fbh[cf], am[rf][cf],0,0,0);
                ax[rf][cf] = __builtin_amdgcn_mfma_f32_16x16x32_f16(fah[rf], fbl[cf], ax[rf][cf],0,0,0);
                ax[rf][cf] = __builtin_amdgcn_mfma_f32_16x16x32_f16(fal[rf], fbh[cf], ax[rf][cf],0,0,0);
            }
        if (do_z) {
#pragma unroll
            for (int i=0;i<8;++i) {
                float a = (float)LAh[arow*LK + seg*8 + i] + (float)LAl[arow*LK + seg*8 + i]*INV2K;
                zacc = fmaf(a, wz[kb*32 + seg*8 + i], zacc);
            }
        }
        if (kb+1 < NT) {
            rah=nah; ral=nal; rwh=nwh; rwl=nwl;
            store_tile((kb+1)&1);
        }
    }

    // z finalize
    if (do_z) {
        float s = zacc;
        s += __shfl_xor(s, 1);
        s += __shfl_xor(s, 2);
        if (seg == 0) {
            float fsz = s + bias[1024];
            float zh = fminf(fmaxf((0.1f*fsz + 1.f)*0.5f, 0.05f), 0.95f);
            z_out[R0+arow] = (noise[R0+arow] < zh) ? 1.f : 0.f;
        }
    }

    __syncthreads();   // all LDS reads done; ex overlay safe
#pragma unroll
    for (int cf=0;cf<2;++cf) {
        int g = ch*2 + cf;
        float bcol = bias[g*256 + j0 + lr];
#pragma unroll
        for (int rf=0;rf<2;++rf)
#pragma unroll
            for (int q=0;q<4;++q) {
                int row = rh*32 + rf*16 + ((lane>>4)<<2) + q;
                float v = am[rf][cf][q] + ax[rf][cf][q]*INV2K + bcol;
                v = (g<3) ? sigf(v) : tanhf(v);
                ex[(g*64+row)*16 + lr] = v;
            }
    }
    __syncthreads();

    // gate combine + state update
    {
        int row = tid>>2, jj = (tid&3)*4;
        float4 f = *(float4*)&ex[(0*64+row)*16 + jj];
        float4 i = *(float4*)&ex[(1*64+row)*16 + jj];
        float4 o = *(float4*)&ex[(2*64+row)*16 + jj];
        float4 g = *(float4*)&ex[(3*64+row)*16 + jj];
        size_t gi = (size_t)(R0+row)*HID + j0 + jj;
        float4 co = *(const float4*)&cbuf[gi];
        float4 cn;
        if (CELL == 1) {
            cn.x = f.x*co.x + i.x*g.x; cn.y = f.y*co.y + i.y*g.y;
            cn.z = f.z*co.z + i.z*g.z; cn.w = f.w*co.w + i.w*g.w;
        } else {
            bool zb = zrow[R0+row] != 0.f;
            cn.x = zb ? (f.x*co.x + i.x*g.x) : co.x;
            cn.y = zb ? (f.y*co.y + i.y*g.y) : co.y;
            cn.z = zb ? (f.z*co.z + i.z*g.z) : co.z;
            cn.w = zb ? (f.w*co.w + i.w*g.w) : co.w;
        }
        *(float4*)&cbuf[gi] = cn;
        float hv[4] = { o.x*tanhf(cn.x), o.y*tanhf(cn.y), o.z*tanhf(cn.z), o.w*tanhf(cn.w) };
        half4 hh, hl;
#pragma unroll
        for (int j=0;j<4;++j) { _Float16 h,l; splitf(hv[j],h,l); hh[j]=h; hl[j]=l; }
        *(half4*)&Hh[gi] = hh;
        *(half4*)&Hl[gi] = hl;
    }
}

// ---------------------------------------------------------------------------
// Tiled parallel GEMM (encoder/head): C = act(A[Mx256] @ W[256xNCOL] + bias).
// Same machinery as cell_k: 64x64 tile, 256 thr, dbuf LDS.
// AIN 0: A fp32; 1: A split. AOUT 0: relu + split out; 1: tanh f32 out.
// ---------------------------------------------------------------------------
template<int AIN, int AOUT, int NCOL>
__global__ __launch_bounds__(256)
void gemm_t(const float* __restrict__ Af,
            const _Float16* __restrict__ Ah_, const _Float16* __restrict__ Al_,
            const _Float16* __restrict__ Bh_, const _Float16* __restrict__ Bl_,
            const float* __restrict__ bias,
            _Float16* __restrict__ Oh, _Float16* __restrict__ Ol,
            float* __restrict__ Of)
{
    constexpr int NT = 8;     // K = 256
    __shared__ __align__(16) char smem[40960];

    const int tid  = threadIdx.x;
    const size_t R0 = (size_t)blockIdx.x*64;
    const int C0   = blockIdx.y*64;
    const int rh   = (tid>>6)&1, ch = tid>>7;
    const int lane = tid&63, lr = lane&15, kq = (lane>>4)<<3;
    const int arow = tid>>2, seg = tid&3;
    const size_t abase = (R0+arow)*256 + seg*8;
    const size_t wbase = (size_t)(C0 + (tid>>2))*256 + seg*8;

    f32x4 am[2][2], ax[2][2];
#pragma unroll
    for (int r=0;r<2;++r)
#pragma unroll
        for (int c=0;c<2;++c){ am[r][c]=(f32x4)0.f; ax[r][c]=(f32x4)0.f; }

    half8 rah, ral, rwh, rwl;
    auto load_tile = [&](int k0, half8& ah, half8& al, half8& wh, half8& wl) {
        if (AIN == 0) {
            float4 a0 = *(const float4*)(Af + abase + k0);
            float4 a1 = *(const float4*)(Af + abase + k0 + 4);
            float av[8] = {a0.x,a0.y,a0.z,a0.w,a1.x,a1.y,a1.z,a1.w};
#pragma unroll
            for (int i=0;i<8;++i){ _Float16 h,l; splitf(av[i],h,l); ah[i]=h; al[i]=l; }
        } else {
            ah = *(const half8*)(Ah_ + abase + k0);
            al = *(const half8*)(Al_ + abase + k0);
        }
        wh = *(const half8*)(Bh_ + wbase + k0);
        wl = *(const half8*)(Bl_ + wbase + k0);
    };
    auto store_tile = [&](int buf) {
        char* bs = smem + buf*20480;
        *(half8*)((_Float16*)(bs        ) + arow*LK + seg*8) = rah;
        *(half8*)((_Float16*)(bs +  5120) + arow*LK + seg*8) = ral;
        *(half8*)((_Float16*)(bs + 10240) + (tid>>2)*LK + seg*8) = rwh;
        *(half8*)((_Float16*)(bs + 15360) + (tid>>2)*LK + seg*8) = rwl;
    };

    load_tile(0, rah, ral, rwh, rwl);
    store_tile(0);

#pragma unroll 2
    for (int kb = 0; kb < NT; ++kb) {
        const int buf = kb & 1;
        half8 nah, nal, nwh, nwl;
        if (kb+1 < NT) load_tile((kb+1)*32, nah, nal, nwh, nwl);
        __syncthreads();
        const char* bs = smem + buf*20480;
        const _Float16* LAh = (const _Float16*)bs;
        const _Float16* LAl = (const _Float16*)(bs +  5120);
        const _Float16* LBh = (const _Float16*)(bs + 10240);
        const _Float16* LBl = (const _Float16*)(bs + 15360);
        half8 fah[2], fal[2], fbh[2], fbl[2];
#pragma unroll
        for (int rf=0;rf<2;++rf) {
            fah[rf] = *(const half8*)(LAh + (rh*32+rf*16+lr)*LK + kq);
            fal[rf] = *(const half8*)(LAl + (rh*32+rf*16+lr)*LK + kq);
        }
#pragma unroll
        for (int cf=0;cf<2;++cf) {
            fbh[cf] = *(const half8*)(LBh + (ch*32+cf*16+lr)*LK + kq);
            fbl[cf] = *(const half8*)(LBl + (ch*32+cf*16+lr)*LK + kq);
        }
#pragma unroll
        for (int cf=0;cf<2;++cf)
#pragma unroll
            for (int rf=0;rf<2;++rf) {
                am[rf][cf] = __builtin_amdgcn_mfma_f32_16x16x32_f16(fah[rf], fbh[cf], am[rf][cf],0,0,0);
                ax[rf][cf] = __builtin_amdgcn_mfma_f32_16x16x32_f16(fah[rf], fbl[cf], ax[rf][cf],0,0,0);
                ax[rf][cf] = __builtin_amdgcn_mfma_f32_16x16x32_f16(fal[rf], fbh[cf], ax[rf][cf],0,0,0);
            }
        if (kb+1 < NT) {
            rah=nah; ral=nal; rwh=nwh; rwl=nwl;
            store_tile((kb+1)&1);
        }
    }

#pragma unroll
    for (int cf=0;cf<2;++cf) {
        int col = C0 + ch*32 + cf*16 + lr;
        float bcol = bias[col];
#pragma unroll
        for (int rf=0;rf<2;++rf)
#pragma unroll
            for (int q=0;q<4;++q) {
                size_t row = R0 + rh*32 + rf*16 + ((lane>>4)<<2) + q;
                float v = am[rf][cf][q] + ax[rf][cf][q]*INV2K + bcol;
                if (AOUT == 0) {
                    v = fmaxf(v, 0.f);
                    _Float16 h,l; splitf(v,h,l);
                    Oh[row*NCOL + col] = h;
                    Ol[row*NCOL + col] = l;
                } else {
                    Of[row*NCOL + col] = tanhf(v);
                }
            }
    }
}

// ---------------------------------------------------------------------------
extern "C" void kernel_launch(void* const* d_in, const int* in_sizes, int n_in,
                              void* d_out, int out_size, void* d_ws, size_t ws_size,
                              hipStream_t stream)
{
    const float* x     = (const float*)d_in[0];
    const float* n1    = (const float*)d_in[1];
    const float* We1   = (const float*)d_in[3];
    const float* be1   = (const float*)d_in[4];
    const float* We2   = (const float*)d_in[5];
    const float* be2   = (const float*)d_in[6];
    const float* U11_1 = (const float*)d_in[7];
    const float* U21_1 = (const float*)d_in[8];
    const float* W01_1 = (const float*)d_in[9];
    const float* b1    = (const float*)d_in[10];
    const float* U11_2 = (const float*)d_in[11];
    const float* W01_2 = (const float*)d_in[12];
    const float* b2    = (const float*)d_in[13];
    const float* Wh    = (const float*)d_in[14];
    const float* bh    = (const float*)d_in[15];
    const float* Wp    = (const float*)d_in[16];
    const float* bp_   = (const float*)d_in[17];
    float* out = (float*)d_out;

    char* p = (char*)d_ws;
    auto alloc = [&](size_t bytes){ char* q = p; p += (bytes + 255) & ~(size_t)255; return q; };
    // shared slot buffer S: slot0 = h2 init (zeros); slot t+1 = xe(t), overwritten by emb(t)=h2n(t)
    _Float16* SH   = (_Float16*)alloc((size_t)(NSTEP+1)*BH*2);
    _Float16* SL   = (_Float16*)alloc((size_t)(NSTEP+1)*BH*2);
    _Float16* TmpH = (_Float16*)alloc((size_t)32*BH*2);       // enc/head chunk temp
    _Float16* TmpL = (_Float16*)alloc((size_t)32*BH*2);
    _Float16* Wt1h = (_Float16*)alloc((size_t)1024*768*2);
    _Float16* Wt1l = (_Float16*)alloc((size_t)1024*768*2);
    _Float16* Wt2h = (_Float16*)alloc((size_t)1024*512*2);
    _Float16* Wt2l = (_Float16*)alloc((size_t)1024*512*2);
    _Float16* We1h = (_Float16*)alloc(256*256*2);
    _Float16* We1l = (_Float16*)alloc(256*256*2);
    _Float16* We2h = (_Float16*)alloc(256*256*2);
    _Float16* We2l = (_Float16*)alloc(256*256*2);
    _Float16* Whh  = (_Float16*)alloc(256*256*2);
    _Float16* Whl  = (_Float16*)alloc(256*256*2);
    _Float16* Wph  = (_Float16*)alloc(64*256*2);
    _Float16* Wpl  = (_Float16*)alloc(64*256*2);
    float*    wz1  = (float*)alloc(768*4);
    _Float16* h1h[2] = { (_Float16*)alloc((size_t)BH*2), (_Float16*)alloc((size_t)BH*2) };
    _Float16* h1l[2] = { (_Float16*)alloc((size_t)BH*2), (_Float16*)alloc((size_t)BH*2) };
    float*    c1   = (float*)alloc((size_t)BH*4);
    float*    c2   = (float*)alloc((size_t)BH*4);
    float*    zb[2] = { (float*)alloc(NB*4), (float*)alloc(NB*4) };
    if (ws_size < (size_t)(p - (char*)d_ws)) return;

    // ---- prep ----
    wsplit_k<<<dim3(3072), 256, 0, stream>>>(W01_1, U21_1, U11_1, 768, 1024, 1025, 256, 512, Wt1h, Wt1l);
    wsplit_k<<<dim3(2048), 256, 0, stream>>>(W01_2, U11_2, nullptr, 512, 1024, 1025, 256, 512, Wt2h, Wt2l);
    wsplit_k<<<dim3(256),  256, 0, stream>>>(We1, nullptr, nullptr, 256, 256, 256, 256, 256, We1h, We1l);
    wsplit_k<<<dim3(256),  256, 0, stream>>>(We2, nullptr, nullptr, 256, 256, 256, 256, 256, We2h, We2l);
    wsplit_k<<<dim3(256),  256, 0, stream>>>(Wh,  nullptr, nullptr, 256, 256, 256, 256, 256, Whh,  Whl);
    wsplit_k<<<dim3(64),   256, 0, stream>>>(Wp,  nullptr, nullptr, 256, 64, 64, 256, 256, Wph, Wpl);
    wz_k<<<dim3(3), 256, 0, stream>>>(W01_1, U21_1, U11_1, wz1);
    init_k<<<dim3(1024), 256, 0, stream>>>(h1h[0], h1l[0], c1, c2, zb[0]);

    // ---- encoder (chunked 8 x 32 steps): xe(t) -> S slot t+1 ----
    for (int c = 0; c < 8; ++c) {
        size_t ro = (size_t)c*32*BH;
        gemm_t<0,0,256><<<dim3(512,4), 256, 0, stream>>>(
            x + ro, nullptr, nullptr, We1h, We1l, be1, TmpH, TmpL, nullptr);
        gemm_t<1,0,256><<<dim3(512,4), 256, 0, stream>>>(
            nullptr, TmpH, TmpL, We2h, We2l, be2, SH + BH + ro, SL + BH + ro, nullptr);
    }
    zslot_k<<<dim3(256), 256, 0, stream>>>(SH, SL);   // h2(-1) = 0

    // ---- recurrence ----
    for (int t = 0; t < NSTEP; ++t) {
        const int cur = t & 1, nxt = cur ^ 1;
        const _Float16* h2h = SH + (size_t)t*BH;
        const _Float16* h2l = SL + (size_t)t*BH;
        const _Float16* xeh = SH + (size_t)(t+1)*BH;
        const _Float16* xel = SL + (size_t)(t+1)*BH;
        cell_k<1><<<dim3(16,16), 256, 0, stream>>>(
            h1h[cur], h1l[cur], h2h, h2l, xeh, xel, zb[cur],
            Wt1h, Wt1l, b1, wz1, n1 + (size_t)t*NB, c1,
            h1h[nxt], h1l[nxt], zb[nxt]);
        cell_k<2><<<dim3(16,16), 256, 0, stream>>>(
            h2h, h2l, h1h[nxt], h1l[nxt], nullptr, nullptr, zb[nxt],
            Wt2h, Wt2l, b2, nullptr, nullptr, c2,
            SH + (size_t)(t+1)*BH, SL + (size_t)(t+1)*BH, nullptr);
    }

    // ---- head (chunked): out = tanh(relu(emb@Wh+bh)@Wp+bp) ----
    for (int c = 0; c < 8; ++c) {
        size_t ro = (size_t)c*32*BH;
        gemm_t<1,0,256><<<dim3(512,4), 256, 0, stream>>>(
            nullptr, SH + BH + ro, SL + BH + ro, Whh, Whl, bh, TmpH, TmpL, nullptr);
        gemm_t<1,1,64><<<dim3(512,1), 256, 0, stream>>>(
            nullptr, TmpH, TmpL, Wph, Wpl, bp_, nullptr, nullptr,
            out + (size_t)c*32*NB*64);
    }
}